// Round 8
// baseline (204.951 us; speedup 1.0000x reference)
//
#include <hip/hip_runtime.h>
#include <hip/hip_bf16.h>
#include <cmath>
#include <stdint.h>

// ---------------- problem constants ----------------
#define K_DIM 1024
#define NH    16
#define HD    64
#define T     2048
#define NTOK  4096   // b*t = 2*2048
#define NBH   32     // b*h

typedef __bf16 bf16x8 __attribute__((ext_vector_type(8)));
typedef float  f32x4  __attribute__((ext_vector_type(4)));
typedef float  f32x16 __attribute__((ext_vector_type(16)));

__device__ __forceinline__ unsigned short f2bf(float f) {
  union { float f; unsigned u; } v; v.f = f;
  unsigned u = v.u;
  return (unsigned short)((u + 0x7FFFu + ((u >> 16) & 1u)) >> 16);
}
// packed round-nearest-even via v_cvt_pk_bf16_f32
__device__ __forceinline__ ushort4 pk4(float a, float b, float c, float d) {
  union { __hip_bfloat162 h[2]; ushort4 u; } r;
  r.h[0] = __float22bfloat162_rn(float2{a, b});
  r.h[1] = __float22bfloat162_rn(float2{c, d});
  return r.u;
}
__device__ __forceinline__ int pk2(float a, float b) {
  union { __hip_bfloat162 h; int u; } r;
  r.h = __float22bfloat162_rn(float2{a, b});
  return r.u;
}

__device__ __forceinline__ void gload16(const void* g, void* l) {
  __builtin_amdgcn_global_load_lds(
      (__attribute__((address_space(1))) void*)(g),
      (__attribute__((address_space(3))) void*)(l),
      16, 0, 0);
}

// ---------------- fp32 -> bf16 conversion ----------------
// Wq is pre-scaled by 0.125*log2(e) so attn can exp2() scores directly.
__global__ void convert_kernel(const float* __restrict__ x,
                               const float* __restrict__ Wq,
                               const float* __restrict__ Wk,
                               const float* __restrict__ Wv,
                               const float* __restrict__ Wo,
                               unsigned short* __restrict__ xb,
                               unsigned short* __restrict__ wqkv,
                               unsigned short* __restrict__ wob)
{
  const size_t NX = (size_t)NTOK * K_DIM;   // 4M
  const size_t NW = (size_t)K_DIM * K_DIM;  // 1M
  size_t i = ((size_t)blockIdx.x * blockDim.x + threadIdx.x) * 4;
  const float* src; unsigned short* dst; size_t off;
  float scale = 1.f;
  if (i < NX)             { src = x;  dst = xb;          off = i; }
  else if (i < NX + NW)   { src = Wq; dst = wqkv;        off = i - NX;
                            scale = 0.18033688011112042f; }
  else if (i < NX + 2*NW) { src = Wk; dst = wqkv + NW;   off = i - NX - NW; }
  else if (i < NX + 3*NW) { src = Wv; dst = wqkv + 2*NW; off = i - NX - 2*NW; }
  else                    { src = Wo; dst = wob;         off = i - NX - 3*NW; }
  float4 v = *(const float4*)(src + off);
  *(ushort4*)(dst + off) = pk4(v.x * scale, v.y * scale, v.z * scale, v.w * scale);
}

// ---------------- B^T GEMM: C[m][n] = sum_k A[m*1024+k] * B[n*1024+k] ----------------
// TMxTN tile, BK=64, 256 threads (2x2 waves). XOR-swizzled LDS (chunk ^= row&7).
// MODE 1 (fused QKV): A=[Wq;Wk;Wv], m=chan in [0,3072), n=token; TM=192 for
//   balanced LDS:MFMA (10 b128 reads per 24 MFMA per kk-step).
//   q/k: packed ushort4 along d; v: b16 scatter to vt[bh][d][t] (t-coalesced).
// MODE 2 (out-proj):  A=Wo, m=chan in [0,1024), n=token -> out[t][chan]+bias, float4.
template <int MODE, int TM, int TN>
__global__ __launch_bounds__(256, 2)
void gemm_bt(const unsigned short* __restrict__ A,
             const unsigned short* __restrict__ B,
             unsigned short* __restrict__ o_q,
             unsigned short* __restrict__ o_k,
             unsigned short* __restrict__ o_v,
             float* __restrict__ o_f,
             const float* __restrict__ bias)
{
  __shared__ unsigned short Asm[TM * 64];
  __shared__ unsigned short Bsm[TN * 64];
  const int tid  = threadIdx.x;
  const int wave = tid >> 6;
  const int lane = tid & 63;
  const int lq   = lane & 15;
  const int quad = lane >> 4;
  const int bm = blockIdx.x, bn = blockIdx.y;
  const int wm = (wave >> 1) * (TM / 2), wn = (wave & 1) * (TN / 2);
  const int MT = TM / 32, NT = TN / 32;

  f32x4 acc[MT][NT];
#pragma unroll
  for (int i = 0; i < MT; ++i)
#pragma unroll
    for (int j = 0; j < NT; ++j) acc[i][j] = (f32x4){0.f, 0.f, 0.f, 0.f};

  const char* Ab = (const char*)(A + (size_t)bm * TM * K_DIM);
  const char* Bb = (const char*)(B + (size_t)bn * TN * K_DIM);

  for (int k0 = 0; k0 < K_DIM; k0 += 64) {
#pragma unroll
    for (int i = 0; i < MT; ++i) {
      int off   = i * 4096 + wave * 1024 + lane * 16;
      int row   = off >> 7;
      int chunk = (off >> 4) & 7;
      int scol  = (chunk ^ (row & 7)) << 4;
      gload16(Ab + (size_t)row * (K_DIM * 2) + (size_t)k0 * 2 + scol,
              (char*)Asm + off - lane * 16);
    }
#pragma unroll
    for (int i = 0; i < NT; ++i) {
      int off   = i * 4096 + wave * 1024 + lane * 16;
      int row   = off >> 7;
      int chunk = (off >> 4) & 7;
      int scol  = (chunk ^ (row & 7)) << 4;
      gload16(Bb + (size_t)row * (K_DIM * 2) + (size_t)k0 * 2 + scol,
              (char*)Bsm + off - lane * 16);
    }
    __syncthreads();
#pragma unroll
    for (int kk = 0; kk < 64; kk += 32) {
      bf16x8 af[MT], bfr[NT];
#pragma unroll
      for (int mt = 0; mt < MT; ++mt) {
        int row = wm + mt * 16 + lq;
        int sw  = (quad + (kk >> 3)) ^ (row & 7);
        af[mt] = *(const bf16x8*)((const char*)Asm + row * 128 + (sw << 4));
      }
#pragma unroll
      for (int nt = 0; nt < NT; ++nt) {
        int row = wn + nt * 16 + lq;
        int sw  = (quad + (kk >> 3)) ^ (row & 7);
        bfr[nt] = *(const bf16x8*)((const char*)Bsm + row * 128 + (sw << 4));
      }
#pragma unroll
      for (int mt = 0; mt < MT; ++mt)
#pragma unroll
        for (int nt = 0; nt < NT; ++nt)
          acc[mt][nt] = __builtin_amdgcn_mfma_f32_16x16x32_bf16(af[mt], bfr[nt], acc[mt][nt], 0, 0, 0);
    }
    __syncthreads();
  }

  // epilogues: acc r=0..3 are 4 consecutive m (chans)
#pragma unroll
  for (int mt = 0; mt < MT; ++mt) {
    int mbase = bm * TM + wm + mt * 16 + quad * 4;
#pragma unroll
    for (int nt = 0; nt < NT; ++nt) {
      int n = bn * TN + wn + nt * 16 + lq;
      if (MODE == 1) {
        int which = mbase >> 10, c = mbase & 1023;   // uniform per 16-row tile
        int h = c >> 6, d0 = c & 63;
        int b = n >> 11, t = n & 2047;
        if (which < 2) {
          ushort4 pk = pk4(acc[mt][nt][0], acc[mt][nt][1], acc[mt][nt][2], acc[mt][nt][3]);
          unsigned short* dst = which ? o_k : o_q;
          *(ushort4*)&dst[((size_t)(b * NH + h) * T + t) * HD + d0] = pk;
        } else {
          // vt[bh][d][t]: consecutive lanes -> consecutive t (coalesced segments)
#pragma unroll
          for (int r = 0; r < 4; ++r)
            o_v[((size_t)(b * NH + h) * HD + d0 + r) * T + t] = f2bf(acc[mt][nt][r]);
        }
      } else {
        float4 bv = *(const float4*)&bias[mbase];
        float4 o;
        o.x = acc[mt][nt][0] + bv.x; o.y = acc[mt][nt][1] + bv.y;
        o.z = acc[mt][nt][2] + bv.z; o.w = acc[mt][nt][3] + bv.w;
        *(float4*)&o_f[(size_t)n * K_DIM + mbase] = o;
      }
    }
  }
}

// ---------------- flash attention (32x32 MFMA, P in regs via permlane32_swap) ----------------
// Round-8 (= r7 resubmit; infra failed before measurement): r6 showed 16x16x16
// MFMA costs the same ~5cy as 16x16x32 (MfmaUtil 22->30.7 at equal work) and
// its b64 V reads conflict (4.19M = 2cy x 2M reads). This version uses
// 32x32x16 everywhere:
//   S^T = K.Q^T (32x32): C gives lane P[key rows][q = lane&31] -- lane's q IS
//   the A-operand row of the PV 32x32x16. The key-octet split across wave
//   halves is fixed with v_permlane32_swap_b32 (VALU pipe, 2 per A-frag):
//   swap(dw0,dw2),swap(dw1,dw3) -> [d0,d1,d2,d3] with zero cndmask.
//   PV: O = P.V, B-frag = Vsm [d][key] rows via b128.
// Per wave-tile: 32 b128 LDS reads (was 32 b128 + 32 b64), 32 MFMA @8cy = 256cy
// (was 480), no lgkmcnt(0). Pipeline unchanged: QK -> syncA -> stage ->
// exp2+swap+PV -> syncB. LDS: Ksm 16K + Vsm 2x16K + Lsm 0.5K.
__global__ __launch_bounds__(256, 2)
void attn_kernel(const unsigned short* __restrict__ Q,
                 const unsigned short* __restrict__ Kb,
                 const unsigned short* __restrict__ Vt,
                 const int* __restrict__ padding,
                 unsigned short* __restrict__ O)
{
  __shared__ unsigned short Ksm[128 * 64];        // 16 KB [key][d], 128B rows, swiz &7
  __shared__ unsigned short Vsm[2][64 * 128];     // 2x16 KB [d][key], 256B rows, swiz &15
  __shared__ float Lsm[4][32];                    // per-wave inv(l) broadcast

  const int tid  = threadIdx.x;
  const int wave = tid >> 6;
  const int lane = tid & 63;
  const int l31  = lane & 31;
  const int hw   = lane >> 5;
  const int bh = blockIdx.x;
  const int qt = blockIdx.y;
  const int b  = bh >> 4;
  const int h  = bh & 15;
  const int qbase = qt * 128 + wave * 32;

  // Q fragments (B-operand of 32x32x16): lane holds Q[q=qbase+l31][d=kk*16+hw*8+j]
  bf16x8 qf[4];
#pragma unroll
  for (int kk = 0; kk < 4; ++kk)
    qf[kk] = *(const bf16x8*)&Q[((size_t)bh * T + qbase + l31) * HD + kk * 16 + hw * 8];

  // O accumulator: C of O = P*V (32x32): o_acc[db][r] = O[q=(r&3)+8*(r>>2)+4*hw][d=db*32+l31]
  f32x16 o_acc[2];
#pragma unroll
  for (int db = 0; db < 2; ++db)
#pragma unroll
    for (int r = 0; r < 16; ++r) o_acc[db][r] = 0.f;
  float l_part = 0.f;

  // stage tile kt into Ksm and Vsm[buf]
  auto stage = [&](int kt, int buf) {
#pragma unroll
    for (int i = 0; i < 4; ++i) {
      int off = i * 4096 + wave * 1024 + lane * 16;
      {  // K: 128B rows
        int row = off >> 7, chunk = (off >> 4) & 7;
        int scol = (chunk ^ (row & 7)) << 4;
        gload16((const char*)Kb + ((size_t)(bh * T + kt * 128 + row) * HD) * 2 + scol,
                (char*)Ksm + off - lane * 16);
      }
      {  // Vt: 256B rows
        int row = off >> 8, chunk = (off >> 4) & 15;
        int scol = (chunk ^ (row & 15)) << 4;
        gload16((const char*)Vt + ((size_t)(bh * HD + row) * T + (size_t)kt * 128) * 2 + scol,
                (char*)Vsm[buf] + off - lane * 16);
      }
    }
  };

  stage(0, 0);
  __syncthreads();

  for (int kt = 0; kt < T / 128; ++kt) {
    const int cur = kt & 1;

    // S^T = K Q^T (32x32x16): st[nt] covers keys nt*32..+31, q = l31
    f32x16 st[4];
#pragma unroll
    for (int nt = 0; nt < 4; ++nt)
#pragma unroll
      for (int r = 0; r < 16; ++r) st[nt][r] = 0.f;
#pragma unroll
    for (int kk = 0; kk < 4; ++kk) {
#pragma unroll
      for (int nt = 0; nt < 4; ++nt) {
        int row = nt * 32 + l31;
        int sw  = (2 * kk + hw) ^ (row & 7);
        bf16x8 kf = *(const bf16x8*)((const char*)Ksm + row * 128 + (sw << 4));
        st[nt] = __builtin_amdgcn_mfma_f32_32x32x16_bf16(kf, qf[kk], st[nt], 0, 0, 0);
      }
    }

    // all waves have consumed Ksm (cheap barrier: no vmcnt pending)
    __syncthreads();

    // prefetch next tile: DMA overlaps exp2 + swap + PV below
    if (kt < T / 128 - 1) stage(kt + 1, cur ^ 1);

    // per 32-key block: exp2 + mask + pack, build PV A-frags via permlane32_swap,
    // then 4 MFMAs (2 key-blocks x 2 d-blocks)
#pragma unroll
    for (int nt = 0; nt < 4; ++nt) {
      int dw[8];
#pragma unroll
      for (int g = 0; g < 4; ++g) {
        // reg r = g*4+i -> key = nt*32 + 8*g + 4*hw + i
        int4 pd = *(const int4*)&padding[b * T + kt * 128 + nt * 32 + g * 8 + hw * 4];
        float p0 = pd.x ? __builtin_amdgcn_exp2f(st[nt][g * 4 + 0]) : 0.f;
        float p1 = pd.y ? __builtin_amdgcn_exp2f(st[nt][g * 4 + 1]) : 0.f;
        float p2 = pd.z ? __builtin_amdgcn_exp2f(st[nt][g * 4 + 2]) : 0.f;
        float p3 = pd.w ? __builtin_amdgcn_exp2f(st[nt][g * 4 + 3]) : 0.f;
        l_part += (p0 + p1) + (p2 + p3);
        dw[g * 2]     = pk2(p0, p1);
        dw[g * 2 + 1] = pk2(p2, p3);
      }
      // A-frags: lane needs P[q=l31][key = kb*16 + hw*8 + {0..7}]
      // swap(a,c): a' = [a_lo | c_lo], c' = [a_hi | c_hi]  (v_permlane32_swap_b32)
      union PA { int d[4]; bf16x8 v; } pa0, pa1;
      {
        int a0 = dw[0], c0 = dw[2];
        int a1 = dw[1], c1 = dw[3];
        asm("v_permlane32_swap_b32 %0, %1" : "+v"(a0), "+v"(c0));
        asm("v_permlane32_swap_b32 %0, %1" : "+v"(a1), "+v"(c1));
        pa0.d[0] = a0; pa0.d[1] = a1; pa0.d[2] = c0; pa0.d[3] = c1;
        int b0 = dw[4], d0 = dw[6];
        int b1 = dw[5], d1 = dw[7];
        asm("v_permlane32_swap_b32 %0, %1" : "+v"(b0), "+v"(d0));
        asm("v_permlane32_swap_b32 %0, %1" : "+v"(b1), "+v"(d1));
        pa1.d[0] = b0; pa1.d[1] = b1; pa1.d[2] = d0; pa1.d[3] = d1;
      }
#pragma unroll
      for (int j = 0; j < 2; ++j) {   // key-block kb = 2*nt + j (16 keys)
        bf16x8 pav = j ? pa1.v : pa0.v;
#pragma unroll
        for (int db = 0; db < 2; ++db) {
          int row = db * 32 + l31;                    // d
          int g2  = 4 * nt + 2 * j + hw;              // global 16B key-chunk
          int sw  = g2 ^ (row & 15);
          bf16x8 vf = *(const bf16x8*)((const char*)Vsm[cur] + row * 256 + (sw << 4));
          o_acc[db] = __builtin_amdgcn_mfma_f32_32x32x16_bf16(pav, vf, o_acc[db], 0, 0, 0);
        }
      }
    }

    // staging drain: mostly complete (exp2+swap+PV covered the DMA)
    __syncthreads();
  }

  // epilogue: lane has l-partial for q=l31 (its hw half's keys); combine halves,
  // broadcast inv per q via tiny LDS (q-rows are half-wave-uniform), store.
  float lsum = l_part + __shfl_xor(l_part, 32);
  float inv  = (lsum > 0.f) ? 1.f / lsum : 0.f;
  Lsm[wave][l31] = inv;            // both halves write identical value
  __syncthreads();
  f32x4 inv4[4];
#pragma unroll
  for (int g = 0; g < 4; ++g)
    inv4[g] = *(const f32x4*)&Lsm[wave][g * 8 + hw * 4];
#pragma unroll
  for (int db = 0; db < 2; ++db) {
#pragma unroll
    for (int r = 0; r < 16; ++r) {
      int qrow = (r & 3) + 8 * (r >> 2) + 4 * hw;
      int t    = qbase + qrow;
      int chan = h * HD + db * 32 + l31;
      O[((size_t)(b * T + t)) * K_DIM + chan] = f2bf(o_acc[db][r] * inv4[r >> 2][r & 3]);
    }
  }
}

// ---------------- launch ----------------
extern "C" void kernel_launch(void* const* d_in, const int* in_sizes, int n_in,
                              void* d_out, int out_size, void* d_ws, size_t ws_size,
                              hipStream_t stream)
{
  const float* x       = (const float*)d_in[0];
  const int*   padding = (const int*)d_in[1];
  const float* Wq      = (const float*)d_in[2];
  const float* Wk      = (const float*)d_in[3];
  const float* Wv      = (const float*)d_in[4];
  const float* Wo      = (const float*)d_in[5];
  const float* bo      = (const float*)d_in[6];
  float* out = (float*)d_out;

  char* ws = (char*)d_ws;
  unsigned short* xb   = (unsigned short*)(ws);                 // 8 MB  x bf16 [4096][1024]
  unsigned short* wqkv = (unsigned short*)(ws + (8u  << 20));   // 6 MB  [Wq;Wk;Wv] bf16
  unsigned short* wob  = (unsigned short*)(ws + (14u << 20));   // 2 MB  Wo bf16
  unsigned short* qb   = (unsigned short*)(ws + (16u << 20));   // 8 MB  q [bh][t][d] (pre-scaled)
  unsigned short* kb   = (unsigned short*)(ws + (24u << 20));   // 8 MB  k [bh][t][d]
  unsigned short* vtb  = (unsigned short*)(ws + (32u << 20));   // 8 MB  v^T [bh][d][t]
  unsigned short* ab   = (unsigned short*)(ws + (40u << 20));   // 8 MB  attn-out [b*t][1024]

  convert_kernel<<<8192, 256, 0, stream>>>(x, Wq, Wk, Wv, Wo, xb, wqkv, wob);

  // fused Q,K,V projections: C[3072 chans][4096 tokens] = [Wq;Wk;Wv] @ x^T
  gemm_bt<1, 192, 128><<<dim3(16, 32), 256, 0, stream>>>(wqkv, xb, qb, kb, vtb, nullptr, nullptr);

  // attention
  attn_kernel<<<dim3(32, 16), 256, 0, stream>>>(qb, kb, vtb, padding, ab);

  // output projection: C[1024 chans][4096 tokens] = Wo @ attn^T -> out[t][chan]+bo
  gemm_bt<2, 64, 128><<<dim3(16, 32), 256, 0, stream>>>(wob, ab, nullptr, nullptr, nullptr, out, bo);
}

// Round 9
// 189.480 us; speedup vs baseline: 1.0817x; 1.0817x over previous
//
#include <hip/hip_runtime.h>
#include <hip/hip_bf16.h>
#include <cmath>
#include <stdint.h>

// ---------------- problem constants ----------------
#define K_DIM 1024
#define NH    16
#define HD    64
#define T     2048
#define NTOK  4096   // b*t = 2*2048
#define NBH   32     // b*h

typedef __bf16 bf16x8 __attribute__((ext_vector_type(8)));
typedef float  f32x4  __attribute__((ext_vector_type(4)));
typedef float  f32x16 __attribute__((ext_vector_type(16)));

__device__ __forceinline__ unsigned short f2bf(float f) {
  union { float f; unsigned u; } v; v.f = f;
  unsigned u = v.u;
  return (unsigned short)((u + 0x7FFFu + ((u >> 16) & 1u)) >> 16);
}
// packed round-nearest-even via v_cvt_pk_bf16_f32
__device__ __forceinline__ ushort4 pk4(float a, float b, float c, float d) {
  union { __hip_bfloat162 h[2]; ushort4 u; } r;
  r.h[0] = __float22bfloat162_rn(float2{a, b});
  r.h[1] = __float22bfloat162_rn(float2{c, d});
  return r.u;
}
__device__ __forceinline__ int pk2(float a, float b) {
  union { __hip_bfloat162 h; int u; } r;
  r.h = __float22bfloat162_rn(float2{a, b});
  return r.u;
}

__device__ __forceinline__ void gload16(const void* g, void* l) {
  __builtin_amdgcn_global_load_lds(
      (__attribute__((address_space(1))) void*)(g),
      (__attribute__((address_space(3))) void*)(l),
      16, 0, 0);
}

// ---------------- fp32 -> bf16 conversion ----------------
// Wq is pre-scaled by 0.125*log2(e) so attn can exp2() scores directly.
__global__ void convert_kernel(const float* __restrict__ x,
                               const float* __restrict__ Wq,
                               const float* __restrict__ Wk,
                               const float* __restrict__ Wv,
                               const float* __restrict__ Wo,
                               unsigned short* __restrict__ xb,
                               unsigned short* __restrict__ wqkv,
                               unsigned short* __restrict__ wob)
{
  const size_t NX = (size_t)NTOK * K_DIM;   // 4M
  const size_t NW = (size_t)K_DIM * K_DIM;  // 1M
  size_t i = ((size_t)blockIdx.x * blockDim.x + threadIdx.x) * 4;
  const float* src; unsigned short* dst; size_t off;
  float scale = 1.f;
  if (i < NX)             { src = x;  dst = xb;          off = i; }
  else if (i < NX + NW)   { src = Wq; dst = wqkv;        off = i - NX;
                            scale = 0.18033688011112042f; }
  else if (i < NX + 2*NW) { src = Wk; dst = wqkv + NW;   off = i - NX - NW; }
  else if (i < NX + 3*NW) { src = Wv; dst = wqkv + 2*NW; off = i - NX - 2*NW; }
  else                    { src = Wo; dst = wob;         off = i - NX - 3*NW; }
  float4 v = *(const float4*)(src + off);
  *(ushort4*)(dst + off) = pk4(v.x * scale, v.y * scale, v.z * scale, v.w * scale);
}

// ---------------- B^T GEMM: C[m][n] = sum_k A[m*1024+k] * B[n*1024+k] ----------------
// TMxTN tile, BK=64, 256 threads (2x2 waves). XOR-swizzled LDS (chunk ^= row&7).
// MODE 1 (fused QKV): A=[Wq;Wk;Wv], m=chan in [0,3072), n=token; TM=192 for
//   balanced LDS:MFMA (10 b128 reads per 24 MFMA per kk-step).
//   q/k: packed ushort4 along d; v: b16 scatter to vt[bh][d][t] (t-coalesced).
// MODE 2 (out-proj):  A=Wo, m=chan in [0,1024), n=token -> out[t][chan]+bias, float4.
template <int MODE, int TM, int TN>
__global__ __launch_bounds__(256, 2)
void gemm_bt(const unsigned short* __restrict__ A,
             const unsigned short* __restrict__ B,
             unsigned short* __restrict__ o_q,
             unsigned short* __restrict__ o_k,
             unsigned short* __restrict__ o_v,
             float* __restrict__ o_f,
             const float* __restrict__ bias)
{
  __shared__ unsigned short Asm[TM * 64];
  __shared__ unsigned short Bsm[TN * 64];
  const int tid  = threadIdx.x;
  const int wave = tid >> 6;
  const int lane = tid & 63;
  const int lq   = lane & 15;
  const int quad = lane >> 4;
  const int bm = blockIdx.x, bn = blockIdx.y;
  const int wm = (wave >> 1) * (TM / 2), wn = (wave & 1) * (TN / 2);
  const int MT = TM / 32, NT = TN / 32;

  f32x4 acc[MT][NT];
#pragma unroll
  for (int i = 0; i < MT; ++i)
#pragma unroll
    for (int j = 0; j < NT; ++j) acc[i][j] = (f32x4){0.f, 0.f, 0.f, 0.f};

  const char* Ab = (const char*)(A + (size_t)bm * TM * K_DIM);
  const char* Bb = (const char*)(B + (size_t)bn * TN * K_DIM);

  for (int k0 = 0; k0 < K_DIM; k0 += 64) {
#pragma unroll
    for (int i = 0; i < MT; ++i) {
      int off   = i * 4096 + wave * 1024 + lane * 16;
      int row   = off >> 7;
      int chunk = (off >> 4) & 7;
      int scol  = (chunk ^ (row & 7)) << 4;
      gload16(Ab + (size_t)row * (K_DIM * 2) + (size_t)k0 * 2 + scol,
              (char*)Asm + off - lane * 16);
    }
#pragma unroll
    for (int i = 0; i < NT; ++i) {
      int off   = i * 4096 + wave * 1024 + lane * 16;
      int row   = off >> 7;
      int chunk = (off >> 4) & 7;
      int scol  = (chunk ^ (row & 7)) << 4;
      gload16(Bb + (size_t)row * (K_DIM * 2) + (size_t)k0 * 2 + scol,
              (char*)Bsm + off - lane * 16);
    }
    __syncthreads();
#pragma unroll
    for (int kk = 0; kk < 64; kk += 32) {
      bf16x8 af[MT], bfr[NT];
#pragma unroll
      for (int mt = 0; mt < MT; ++mt) {
        int row = wm + mt * 16 + lq;
        int sw  = (quad + (kk >> 3)) ^ (row & 7);
        af[mt] = *(const bf16x8*)((const char*)Asm + row * 128 + (sw << 4));
      }
#pragma unroll
      for (int nt = 0; nt < NT; ++nt) {
        int row = wn + nt * 16 + lq;
        int sw  = (quad + (kk >> 3)) ^ (row & 7);
        bfr[nt] = *(const bf16x8*)((const char*)Bsm + row * 128 + (sw << 4));
      }
#pragma unroll
      for (int mt = 0; mt < MT; ++mt)
#pragma unroll
        for (int nt = 0; nt < NT; ++nt)
          acc[mt][nt] = __builtin_amdgcn_mfma_f32_16x16x32_bf16(af[mt], bfr[nt], acc[mt][nt], 0, 0, 0);
    }
    __syncthreads();
  }

  // epilogues: acc r=0..3 are 4 consecutive m (chans)
#pragma unroll
  for (int mt = 0; mt < MT; ++mt) {
    int mbase = bm * TM + wm + mt * 16 + quad * 4;
#pragma unroll
    for (int nt = 0; nt < NT; ++nt) {
      int n = bn * TN + wn + nt * 16 + lq;
      if (MODE == 1) {
        int which = mbase >> 10, c = mbase & 1023;   // uniform per 16-row tile
        int h = c >> 6, d0 = c & 63;
        int b = n >> 11, t = n & 2047;
        if (which < 2) {
          ushort4 pk = pk4(acc[mt][nt][0], acc[mt][nt][1], acc[mt][nt][2], acc[mt][nt][3]);
          unsigned short* dst = which ? o_k : o_q;
          *(ushort4*)&dst[((size_t)(b * NH + h) * T + t) * HD + d0] = pk;
        } else {
          // vt[bh][d][t]: consecutive lanes -> consecutive t (coalesced segments)
#pragma unroll
          for (int r = 0; r < 4; ++r)
            o_v[((size_t)(b * NH + h) * HD + d0 + r) * T + t] = f2bf(acc[mt][nt][r]);
        }
      } else {
        float4 bv = *(const float4*)&bias[mbase];
        float4 o;
        o.x = acc[mt][nt][0] + bv.x; o.y = acc[mt][nt][1] + bv.y;
        o.z = acc[mt][nt][2] + bv.z; o.w = acc[mt][nt][3] + bv.w;
        *(float4*)&o_f[(size_t)n * K_DIM + mbase] = o;
      }
    }
  }
}

// ---------------- flash attention (32x32 MFMA, per-block fusion, dbuf K+V) ----------------
// Round-9: r8 verified the 32x32 layout algebra (passed) but ran 80us:
//  (a) K-read 4-way bank conflict (2.1M = 2cy x 1.05M reads): rows r,r+8,r+16,r+24
//      shared a slot. Fix: f_K(row) = (row&7) ^ ((row>>3)&3), both staging+read.
//  (b) +20us pure stall vs r2 (VALU-busy and MFMA-busy identical): st[4]=64 live
//      VGPRs + o_acc 32 + qf 16 > 88 allocated -> scratch. Fix: per-32-key-block
//      fusion (QK_nt -> softmax_nt -> PV_nt), st = 16 regs.
//  (c) Ksm double-buffered -> syncA eliminated, ONE barrier per tile; staging
//      issued at tile start, covered by the whole compute phase.
// LDS: Ksm 2x16K + Vsm 2x16K + Lsm 0.5K = 64.5KB -> 2 blocks/CU.
__global__ __launch_bounds__(256, 2)
void attn_kernel(const unsigned short* __restrict__ Q,
                 const unsigned short* __restrict__ Kb,
                 const unsigned short* __restrict__ Vt,
                 const int* __restrict__ padding,
                 unsigned short* __restrict__ O)
{
  __shared__ unsigned short Ksm[2][128 * 64];     // 2x16 KB [key][d], 128B rows, swiz f_K
  __shared__ unsigned short Vsm[2][64 * 128];     // 2x16 KB [d][key], 256B rows, swiz &15
  __shared__ float Lsm[4][32];                    // per-wave inv(l) broadcast

  const int tid  = threadIdx.x;
  const int wave = tid >> 6;
  const int lane = tid & 63;
  const int l31  = lane & 31;
  const int hw   = lane >> 5;
  const int bh = blockIdx.x;
  const int qt = blockIdx.y;
  const int b  = bh >> 4;
  const int h  = bh & 15;
  const int qbase = qt * 128 + wave * 32;
  const int fk   = (l31 & 7) ^ ((l31 >> 3) & 3);  // K read swizzle (row-class stable)

  // Q fragments (B-operand of 32x32x16): lane holds Q[q=qbase+l31][d=kk*16+hw*8+j]
  bf16x8 qf[4];
#pragma unroll
  for (int kk = 0; kk < 4; ++kk)
    qf[kk] = *(const bf16x8*)&Q[((size_t)bh * T + qbase + l31) * HD + kk * 16 + hw * 8];

  // O accumulator: C of O = P*V (32x32): o_acc[db][r] = O[q=(r&3)+8*(r>>2)+4*hw][d=db*32+l31]
  f32x16 o_acc[2];
#pragma unroll
  for (int db = 0; db < 2; ++db)
#pragma unroll
    for (int r = 0; r < 16; ++r) o_acc[db][r] = 0.f;
  float l_part = 0.f;

  // stage tile kt into Ksm[buf] and Vsm[buf]
  auto stage = [&](int kt, int buf) {
#pragma unroll
    for (int i = 0; i < 4; ++i) {
      int off = i * 4096 + wave * 1024 + lane * 16;
      {  // K: 128B rows, f_K = (row&7)^((row>>3)&3)
        int row = off >> 7, chunk = (off >> 4) & 7;
        int f   = (row & 7) ^ ((row >> 3) & 3);
        int scol = (chunk ^ f) << 4;
        gload16((const char*)Kb + ((size_t)(bh * T + kt * 128 + row) * HD) * 2 + scol,
                (char*)Ksm[buf] + off - lane * 16);
      }
      {  // Vt: 256B rows, f_V = row&15
        int row = off >> 8, chunk = (off >> 4) & 15;
        int scol = (chunk ^ (row & 15)) << 4;
        gload16((const char*)Vt + ((size_t)(bh * HD + row) * T + (size_t)kt * 128) * 2 + scol,
                (char*)Vsm[buf] + off - lane * 16);
      }
    }
  };

  stage(0, 0);
  __syncthreads();

  for (int kt = 0; kt < T / 128; ++kt) {
    const int cur = kt & 1;

    // issue next-tile staging FIRST: DMA (vmcnt) overlaps the whole compute
    // phase below; drained by the end-of-tile barrier.
    if (kt < T / 128 - 1) stage(kt + 1, cur ^ 1);

    // per 32-key block: QK (st = 16 regs) -> exp2/mask/pack -> permlane -> PV
#pragma unroll
    for (int nt = 0; nt < 4; ++nt) {
      // S^T = K Q^T (32x32x16): keys nt*32..+31, q = l31
      f32x16 st;
#pragma unroll
      for (int r = 0; r < 16; ++r) st[r] = 0.f;
#pragma unroll
      for (int kk = 0; kk < 4; ++kk) {
        int row = nt * 32 + l31;
        int sw  = (2 * kk + hw) ^ fk;
        bf16x8 kf = *(const bf16x8*)((const char*)Ksm[cur] + row * 128 + (sw << 4));
        st = __builtin_amdgcn_mfma_f32_32x32x16_bf16(kf, qf[kk], st, 0, 0, 0);
      }

      // exp2 + padding mask + row-sum partials; pack pairs as bf16 dwords
      int dw[8];
#pragma unroll
      for (int g = 0; g < 4; ++g) {
        // reg r = g*4+i -> key = nt*32 + 8*g + 4*hw + i
        int4 pd = *(const int4*)&padding[b * T + kt * 128 + nt * 32 + g * 8 + hw * 4];
        float p0 = pd.x ? __builtin_amdgcn_exp2f(st[g * 4 + 0]) : 0.f;
        float p1 = pd.y ? __builtin_amdgcn_exp2f(st[g * 4 + 1]) : 0.f;
        float p2 = pd.z ? __builtin_amdgcn_exp2f(st[g * 4 + 2]) : 0.f;
        float p3 = pd.w ? __builtin_amdgcn_exp2f(st[g * 4 + 3]) : 0.f;
        l_part += (p0 + p1) + (p2 + p3);
        dw[g * 2]     = pk2(p0, p1);
        dw[g * 2 + 1] = pk2(p2, p3);
      }
      // A-frags: lane needs P[q=l31][key = kb*16 + hw*8 + {0..7}]
      // swap(a,c): a' = [a_lo | c_lo], c' = [a_hi | c_hi]  (v_permlane32_swap_b32)
      union PA { int d[4]; bf16x8 v; } pa0, pa1;
      {
        int a0 = dw[0], c0 = dw[2];
        int a1 = dw[1], c1 = dw[3];
        asm("v_permlane32_swap_b32 %0, %1" : "+v"(a0), "+v"(c0));
        asm("v_permlane32_swap_b32 %0, %1" : "+v"(a1), "+v"(c1));
        pa0.d[0] = a0; pa0.d[1] = a1; pa0.d[2] = c0; pa0.d[3] = c1;
        int b0 = dw[4], d0 = dw[6];
        int b1 = dw[5], d1 = dw[7];
        asm("v_permlane32_swap_b32 %0, %1" : "+v"(b0), "+v"(d0));
        asm("v_permlane32_swap_b32 %0, %1" : "+v"(b1), "+v"(d1));
        pa1.d[0] = b0; pa1.d[1] = b1; pa1.d[2] = d0; pa1.d[3] = d1;
      }
      // O += P*V : 2 key-blocks x 2 d-blocks
#pragma unroll
      for (int j = 0; j < 2; ++j) {
        bf16x8 pav = j ? pa1.v : pa0.v;
#pragma unroll
        for (int db = 0; db < 2; ++db) {
          int row = db * 32 + l31;                    // d
          int g2  = 4 * nt + 2 * j + hw;              // global 16B key-chunk
          int sw  = g2 ^ (row & 15);
          bf16x8 vf = *(const bf16x8*)((const char*)Vsm[cur] + row * 256 + (sw << 4));
          o_acc[db] = __builtin_amdgcn_mfma_f32_32x32x16_bf16(pav, vf, o_acc[db], 0, 0, 0);
        }
      }
    }

    // single barrier per tile: drains staging DMA (vmcnt) + orders buffer reuse
    __syncthreads();
  }

  // epilogue: lane has l-partial for q=l31 (its hw half's keys); combine halves,
  // broadcast inv per q via tiny LDS (q-rows are half-wave-uniform), store.
  float lsum = l_part + __shfl_xor(l_part, 32);
  float inv  = (lsum > 0.f) ? 1.f / lsum : 0.f;
  Lsm[wave][l31] = inv;            // both halves write identical value
  __syncthreads();
  f32x4 inv4[4];
#pragma unroll
  for (int g = 0; g < 4; ++g)
    inv4[g] = *(const f32x4*)&Lsm[wave][g * 8 + hw * 4];
#pragma unroll
  for (int db = 0; db < 2; ++db) {
#pragma unroll
    for (int r = 0; r < 16; ++r) {
      int qrow = (r & 3) + 8 * (r >> 2) + 4 * hw;
      int t    = qbase + qrow;
      int chan = h * HD + db * 32 + l31;
      O[((size_t)(b * T + t)) * K_DIM + chan] = f2bf(o_acc[db][r] * inv4[r >> 2][r & 3]);
    }
  }
}

// ---------------- launch ----------------
extern "C" void kernel_launch(void* const* d_in, const int* in_sizes, int n_in,
                              void* d_out, int out_size, void* d_ws, size_t ws_size,
                              hipStream_t stream)
{
  const float* x       = (const float*)d_in[0];
  const int*   padding = (const int*)d_in[1];
  const float* Wq      = (const float*)d_in[2];
  const float* Wk      = (const float*)d_in[3];
  const float* Wv      = (const float*)d_in[4];
  const float* Wo      = (const float*)d_in[5];
  const float* bo      = (const float*)d_in[6];
  float* out = (float*)d_out;

  char* ws = (char*)d_ws;
  unsigned short* xb   = (unsigned short*)(ws);                 // 8 MB  x bf16 [4096][1024]
  unsigned short* wqkv = (unsigned short*)(ws + (8u  << 20));   // 6 MB  [Wq;Wk;Wv] bf16
  unsigned short* wob  = (unsigned short*)(ws + (14u << 20));   // 2 MB  Wo bf16
  unsigned short* qb   = (unsigned short*)(ws + (16u << 20));   // 8 MB  q [bh][t][d] (pre-scaled)
  unsigned short* kb   = (unsigned short*)(ws + (24u << 20));   // 8 MB  k [bh][t][d]
  unsigned short* vtb  = (unsigned short*)(ws + (32u << 20));   // 8 MB  v^T [bh][d][t]
  unsigned short* ab   = (unsigned short*)(ws + (40u << 20));   // 8 MB  attn-out [b*t][1024]

  convert_kernel<<<8192, 256, 0, stream>>>(x, Wq, Wk, Wv, Wo, xb, wqkv, wob);

  // fused Q,K,V projections: C[3072 chans][4096 tokens] = [Wq;Wk;Wv] @ x^T
  gemm_bt<1, 192, 128><<<dim3(16, 32), 256, 0, stream>>>(wqkv, xb, qb, kb, vtb, nullptr, nullptr);

  // attention
  attn_kernel<<<dim3(32, 16), 256, 0, stream>>>(qb, kb, vtb, padding, ab);

  // output projection: C[1024 chans][4096 tokens] = Wo @ attn^T -> out[t][chan]+bo
  gemm_bt<2, 64, 128><<<dim3(16, 32), 256, 0, stream>>>(wob, ab, nullptr, nullptr, nullptr, out, bo);
}

// Round 10
// 188.403 us; speedup vs baseline: 1.0878x; 1.0057x over previous
//
#include <hip/hip_runtime.h>
#include <hip/hip_bf16.h>
#include <cmath>
#include <stdint.h>

// ---------------- problem constants ----------------
#define K_DIM 1024
#define NH    16
#define HD    64
#define T     2048
#define NTOK  4096   // b*t = 2*2048
#define NBH   32     // b*h

typedef __bf16 bf16x8 __attribute__((ext_vector_type(8)));
typedef float  f32x4  __attribute__((ext_vector_type(4)));
typedef float  f32x16 __attribute__((ext_vector_type(16)));

__device__ __forceinline__ unsigned short f2bf(float f) {
  union { float f; unsigned u; } v; v.f = f;
  unsigned u = v.u;
  return (unsigned short)((u + 0x7FFFu + ((u >> 16) & 1u)) >> 16);
}
// packed round-nearest-even via v_cvt_pk_bf16_f32
__device__ __forceinline__ ushort4 pk4(float a, float b, float c, float d) {
  union { __hip_bfloat162 h[2]; ushort4 u; } r;
  r.h[0] = __float22bfloat162_rn(float2{a, b});
  r.h[1] = __float22bfloat162_rn(float2{c, d});
  return r.u;
}
__device__ __forceinline__ int pk2(float a, float b) {
  union { __hip_bfloat162 h; int u; } r;
  r.h = __float22bfloat162_rn(float2{a, b});
  return r.u;
}

__device__ __forceinline__ void gload16(const void* g, void* l) {
  __builtin_amdgcn_global_load_lds(
      (__attribute__((address_space(1))) void*)(g),
      (__attribute__((address_space(3))) void*)(l),
      16, 0, 0);
}

// ---------------- fp32 -> bf16 conversion ----------------
// Wq is pre-scaled by 0.125*log2(e) so attn can exp2() scores directly.
__global__ void convert_kernel(const float* __restrict__ x,
                               const float* __restrict__ Wq,
                               const float* __restrict__ Wk,
                               const float* __restrict__ Wv,
                               const float* __restrict__ Wo,
                               unsigned short* __restrict__ xb,
                               unsigned short* __restrict__ wqkv,
                               unsigned short* __restrict__ wob)
{
  const size_t NX = (size_t)NTOK * K_DIM;   // 4M
  const size_t NW = (size_t)K_DIM * K_DIM;  // 1M
  size_t i = ((size_t)blockIdx.x * blockDim.x + threadIdx.x) * 4;
  const float* src; unsigned short* dst; size_t off;
  float scale = 1.f;
  if (i < NX)             { src = x;  dst = xb;          off = i; }
  else if (i < NX + NW)   { src = Wq; dst = wqkv;        off = i - NX;
                            scale = 0.18033688011112042f; }
  else if (i < NX + 2*NW) { src = Wk; dst = wqkv + NW;   off = i - NX - NW; }
  else if (i < NX + 3*NW) { src = Wv; dst = wqkv + 2*NW; off = i - NX - 2*NW; }
  else                    { src = Wo; dst = wob;         off = i - NX - 3*NW; }
  float4 v = *(const float4*)(src + off);
  *(ushort4*)(dst + off) = pk4(v.x * scale, v.y * scale, v.z * scale, v.w * scale);
}

// ---------------- B^T GEMM: C[m][n] = sum_k A[m*1024+k] * B[n*1024+k] ----------------
// TMxTN tile, BK=64, 256 threads (2x2 waves). XOR-swizzled LDS (chunk ^= row&7).
// MODE 1 (fused QKV): A=[Wq;Wk;Wv], m=chan in [0,3072), n=token; TM=192 for
//   balanced LDS:MFMA (10 b128 reads per 24 MFMA per kk-step).
//   q/k: packed ushort4 along d; v: b16 scatter to vt[bh][d][t] (t-coalesced).
// MODE 2 (out-proj):  A=Wo, m=chan in [0,1024), n=token -> out[t][chan]+bias, float4.
template <int MODE, int TM, int TN>
__global__ __launch_bounds__(256, 2)
void gemm_bt(const unsigned short* __restrict__ A,
             const unsigned short* __restrict__ B,
             unsigned short* __restrict__ o_q,
             unsigned short* __restrict__ o_k,
             unsigned short* __restrict__ o_v,
             float* __restrict__ o_f,
             const float* __restrict__ bias)
{
  __shared__ unsigned short Asm[TM * 64];
  __shared__ unsigned short Bsm[TN * 64];
  const int tid  = threadIdx.x;
  const int wave = tid >> 6;
  const int lane = tid & 63;
  const int lq   = lane & 15;
  const int quad = lane >> 4;
  const int bm = blockIdx.x, bn = blockIdx.y;
  const int wm = (wave >> 1) * (TM / 2), wn = (wave & 1) * (TN / 2);
  const int MT = TM / 32, NT = TN / 32;

  f32x4 acc[MT][NT];
#pragma unroll
  for (int i = 0; i < MT; ++i)
#pragma unroll
    for (int j = 0; j < NT; ++j) acc[i][j] = (f32x4){0.f, 0.f, 0.f, 0.f};

  const char* Ab = (const char*)(A + (size_t)bm * TM * K_DIM);
  const char* Bb = (const char*)(B + (size_t)bn * TN * K_DIM);

  for (int k0 = 0; k0 < K_DIM; k0 += 64) {
#pragma unroll
    for (int i = 0; i < MT; ++i) {
      int off   = i * 4096 + wave * 1024 + lane * 16;
      int row   = off >> 7;
      int chunk = (off >> 4) & 7;
      int scol  = (chunk ^ (row & 7)) << 4;
      gload16(Ab + (size_t)row * (K_DIM * 2) + (size_t)k0 * 2 + scol,
              (char*)Asm + off - lane * 16);
    }
#pragma unroll
    for (int i = 0; i < NT; ++i) {
      int off   = i * 4096 + wave * 1024 + lane * 16;
      int row   = off >> 7;
      int chunk = (off >> 4) & 7;
      int scol  = (chunk ^ (row & 7)) << 4;
      gload16(Bb + (size_t)row * (K_DIM * 2) + (size_t)k0 * 2 + scol,
              (char*)Bsm + off - lane * 16);
    }
    __syncthreads();
#pragma unroll
    for (int kk = 0; kk < 64; kk += 32) {
      bf16x8 af[MT], bfr[NT];
#pragma unroll
      for (int mt = 0; mt < MT; ++mt) {
        int row = wm + mt * 16 + lq;
        int sw  = (quad + (kk >> 3)) ^ (row & 7);
        af[mt] = *(const bf16x8*)((const char*)Asm + row * 128 + (sw << 4));
      }
#pragma unroll
      for (int nt = 0; nt < NT; ++nt) {
        int row = wn + nt * 16 + lq;
        int sw  = (quad + (kk >> 3)) ^ (row & 7);
        bfr[nt] = *(const bf16x8*)((const char*)Bsm + row * 128 + (sw << 4));
      }
#pragma unroll
      for (int mt = 0; mt < MT; ++mt)
#pragma unroll
        for (int nt = 0; nt < NT; ++nt)
          acc[mt][nt] = __builtin_amdgcn_mfma_f32_16x16x32_bf16(af[mt], bfr[nt], acc[mt][nt], 0, 0, 0);
    }
    __syncthreads();
  }

  // epilogues: acc r=0..3 are 4 consecutive m (chans)
#pragma unroll
  for (int mt = 0; mt < MT; ++mt) {
    int mbase = bm * TM + wm + mt * 16 + quad * 4;
#pragma unroll
    for (int nt = 0; nt < NT; ++nt) {
      int n = bn * TN + wn + nt * 16 + lq;
      if (MODE == 1) {
        int which = mbase >> 10, c = mbase & 1023;   // uniform per 16-row tile
        int h = c >> 6, d0 = c & 63;
        int b = n >> 11, t = n & 2047;
        if (which < 2) {
          ushort4 pk = pk4(acc[mt][nt][0], acc[mt][nt][1], acc[mt][nt][2], acc[mt][nt][3]);
          unsigned short* dst = which ? o_k : o_q;
          *(ushort4*)&dst[((size_t)(b * NH + h) * T + t) * HD + d0] = pk;
        } else {
          // vt[bh][d][t]: consecutive lanes -> consecutive t (coalesced segments)
#pragma unroll
          for (int r = 0; r < 4; ++r)
            o_v[((size_t)(b * NH + h) * HD + d0 + r) * T + t] = f2bf(acc[mt][nt][r]);
        }
      } else {
        float4 bv = *(const float4*)&bias[mbase];
        float4 o;
        o.x = acc[mt][nt][0] + bv.x; o.y = acc[mt][nt][1] + bv.y;
        o.z = acc[mt][nt][2] + bv.z; o.w = acc[mt][nt][3] + bv.w;
        *(float4*)&o_f[(size_t)n * K_DIM + mbase] = o;
      }
    }
  }
}

// ---------------- flash attention (32x32 MFMA, phase-separated, ILP-restored) ----------------
// Round-10: r9 fixed conflicts (2.1M->0) but kept a ~12us dependency stall vs r2:
// per-block fusion had 1 QK chain (4-deep) + 2 PV chains (8-deep) and serial
// QK->SM->PV per 32 keys. This round restores r2-style ILP at the 32x32 shape:
//  - QK phase: all 4 st[nt] chains interleaved (kk-outer) -> 4-way MFMA ILP
//  - softmax phase: all nt; P packed to A-frags via permlane32_swap; 2 l-partials
//  - PV phase: accumulators split by key-block j -> oj[2][2] = 4 independent
//    chains, 4-deep each (was 2 chains 8-deep)
// Swizzles/dbuf/single-barrier/stage-first unchanged from r9 (conflicts 0).
// VGPR peak ~170 (free: occupancy LDS-capped at 2 blocks/CU, cap 256).
__global__ __launch_bounds__(256, 2)
void attn_kernel(const unsigned short* __restrict__ Q,
                 const unsigned short* __restrict__ Kb,
                 const unsigned short* __restrict__ Vt,
                 const int* __restrict__ padding,
                 unsigned short* __restrict__ O)
{
  __shared__ unsigned short Ksm[2][128 * 64];     // 2x16 KB [key][d], 128B rows, swiz f_K
  __shared__ unsigned short Vsm[2][64 * 128];     // 2x16 KB [d][key], 256B rows, swiz &15
  __shared__ float Lsm[4][32];                    // per-wave inv(l) broadcast

  const int tid  = threadIdx.x;
  const int wave = tid >> 6;
  const int lane = tid & 63;
  const int l31  = lane & 31;
  const int hw   = lane >> 5;
  const int bh = blockIdx.x;
  const int qt = blockIdx.y;
  const int b  = bh >> 4;
  const int h  = bh & 15;
  const int qbase = qt * 128 + wave * 32;
  const int fk   = (l31 & 7) ^ ((l31 >> 3) & 3);  // K read swizzle (row-class stable)

  // Q fragments (B-operand of 32x32x16): lane holds Q[q=qbase+l31][d=kk*16+hw*8+j]
  bf16x8 qf[4];
#pragma unroll
  for (int kk = 0; kk < 4; ++kk)
    qf[kk] = *(const bf16x8*)&Q[((size_t)bh * T + qbase + l31) * HD + kk * 16 + hw * 8];

  // PV accumulators split by key-block parity j: oj[j][db]; summed in epilogue.
  // Layout (32x32 C): oj[j][db][r] = O_j[q=(r&3)+8*(r>>2)+4*hw][d=db*32+l31]
  f32x16 oj[2][2];
#pragma unroll
  for (int j = 0; j < 2; ++j)
#pragma unroll
    for (int db = 0; db < 2; ++db)
#pragma unroll
      for (int r = 0; r < 16; ++r) oj[j][db][r] = 0.f;
  float lp0 = 0.f, lp1 = 0.f;

  // stage tile kt into Ksm[buf] and Vsm[buf]
  auto stage = [&](int kt, int buf) {
#pragma unroll
    for (int i = 0; i < 4; ++i) {
      int off = i * 4096 + wave * 1024 + lane * 16;
      {  // K: 128B rows, f_K = (row&7)^((row>>3)&3)
        int row = off >> 7, chunk = (off >> 4) & 7;
        int f   = (row & 7) ^ ((row >> 3) & 3);
        int scol = (chunk ^ f) << 4;
        gload16((const char*)Kb + ((size_t)(bh * T + kt * 128 + row) * HD) * 2 + scol,
                (char*)Ksm[buf] + off - lane * 16);
      }
      {  // Vt: 256B rows, f_V = row&15
        int row = off >> 8, chunk = (off >> 4) & 15;
        int scol = (chunk ^ (row & 15)) << 4;
        gload16((const char*)Vt + ((size_t)(bh * HD + row) * T + (size_t)kt * 128) * 2 + scol,
                (char*)Vsm[buf] + off - lane * 16);
      }
    }
  };

  stage(0, 0);
  __syncthreads();

  for (int kt = 0; kt < T / 128; ++kt) {
    const int cur = kt & 1;

    // issue next-tile staging FIRST: DMA (vmcnt) overlaps the whole compute
    // phase below; drained by the end-of-tile barrier.
    if (kt < T / 128 - 1) stage(kt + 1, cur ^ 1);

    // ---- QK phase: S^T = K Q^T, 4 independent chains (kk-outer) ----
    f32x16 st[4];
#pragma unroll
    for (int nt = 0; nt < 4; ++nt)
#pragma unroll
      for (int r = 0; r < 16; ++r) st[nt][r] = 0.f;
#pragma unroll
    for (int kk = 0; kk < 4; ++kk) {
      int sw = (2 * kk + hw) ^ fk;
#pragma unroll
      for (int nt = 0; nt < 4; ++nt) {
        int row = nt * 32 + l31;
        bf16x8 kf = *(const bf16x8*)((const char*)Ksm[cur] + row * 128 + (sw << 4));
        st[nt] = __builtin_amdgcn_mfma_f32_32x32x16_bf16(kf, qf[kk], st[nt], 0, 0, 0);
      }
    }

    // ---- softmax phase: exp2 + mask + partial sums + pack to PV A-frags ----
    // paA[nt] = keys (2nt)*16.., paB[nt] = keys (2nt+1)*16..
    union PA { int d[4]; bf16x8 v; } paA[4], paB[4];
#pragma unroll
    for (int nt = 0; nt < 4; ++nt) {
      int dw[8];
#pragma unroll
      for (int g = 0; g < 4; ++g) {
        // reg r = g*4+i -> key = nt*32 + 8*g + 4*hw + i
        int4 pd = *(const int4*)&padding[b * T + kt * 128 + nt * 32 + g * 8 + hw * 4];
        float p0 = pd.x ? __builtin_amdgcn_exp2f(st[nt][g * 4 + 0]) : 0.f;
        float p1 = pd.y ? __builtin_amdgcn_exp2f(st[nt][g * 4 + 1]) : 0.f;
        float p2 = pd.z ? __builtin_amdgcn_exp2f(st[nt][g * 4 + 2]) : 0.f;
        float p3 = pd.w ? __builtin_amdgcn_exp2f(st[nt][g * 4 + 3]) : 0.f;
        if (g & 1) lp1 += (p0 + p1) + (p2 + p3);
        else       lp0 += (p0 + p1) + (p2 + p3);
        dw[g * 2]     = pk2(p0, p1);
        dw[g * 2 + 1] = pk2(p2, p3);
      }
      // swap(a,c): a' = [a_lo | c_lo], c' = [a_hi | c_hi]  (v_permlane32_swap_b32)
      {
        int a0 = dw[0], c0 = dw[2];
        int a1 = dw[1], c1 = dw[3];
        asm("v_permlane32_swap_b32 %0, %1" : "+v"(a0), "+v"(c0));
        asm("v_permlane32_swap_b32 %0, %1" : "+v"(a1), "+v"(c1));
        paA[nt].d[0] = a0; paA[nt].d[1] = a1; paA[nt].d[2] = c0; paA[nt].d[3] = c1;
        int b0 = dw[4], d0 = dw[6];
        int b1 = dw[5], d1 = dw[7];
        asm("v_permlane32_swap_b32 %0, %1" : "+v"(b0), "+v"(d0));
        asm("v_permlane32_swap_b32 %0, %1" : "+v"(b1), "+v"(d1));
        paB[nt].d[0] = b0; paB[nt].d[1] = b1; paB[nt].d[2] = d0; paB[nt].d[3] = d1;
      }
    }

    // ---- PV phase: O += P*V, 4 independent chains (oj[j][db]) ----
#pragma unroll
    for (int nt = 0; nt < 4; ++nt) {
#pragma unroll
      for (int j = 0; j < 2; ++j) {
        bf16x8 pav = j ? paB[nt].v : paA[nt].v;
#pragma unroll
        for (int db = 0; db < 2; ++db) {
          int row = db * 32 + l31;                    // d
          int g2  = 4 * nt + 2 * j + hw;              // global 16B key-chunk
          int sw  = g2 ^ (row & 15);
          bf16x8 vf = *(const bf16x8*)((const char*)Vsm[cur] + row * 256 + (sw << 4));
          oj[j][db] = __builtin_amdgcn_mfma_f32_32x32x16_bf16(pav, vf, oj[j][db], 0, 0, 0);
        }
      }
    }

    // single barrier per tile: drains staging DMA (vmcnt) + orders buffer reuse
    __syncthreads();
  }

  // epilogue: sum j-split accumulators; lane has l-partial for q=l31 (its hw
  // half's keys); combine halves, broadcast inv per q via tiny LDS, store.
  float lsum = (lp0 + lp1);
  lsum += __shfl_xor(lsum, 32);
  float inv  = (lsum > 0.f) ? 1.f / lsum : 0.f;
  Lsm[wave][l31] = inv;            // both halves write identical value
  __syncthreads();
  f32x4 inv4[4];
#pragma unroll
  for (int g = 0; g < 4; ++g)
    inv4[g] = *(const f32x4*)&Lsm[wave][g * 8 + hw * 4];
#pragma unroll
  for (int db = 0; db < 2; ++db) {
#pragma unroll
    for (int r = 0; r < 16; ++r) {
      int qrow = (r & 3) + 8 * (r >> 2) + 4 * hw;
      int t    = qbase + qrow;
      int chan = h * HD + db * 32 + l31;
      float ov = oj[0][db][r] + oj[1][db][r];
      O[((size_t)(b * T + t)) * K_DIM + chan] = f2bf(ov * inv4[r >> 2][r & 3]);
    }
  }
}

// ---------------- launch ----------------
extern "C" void kernel_launch(void* const* d_in, const int* in_sizes, int n_in,
                              void* d_out, int out_size, void* d_ws, size_t ws_size,
                              hipStream_t stream)
{
  const float* x       = (const float*)d_in[0];
  const int*   padding = (const int*)d_in[1];
  const float* Wq      = (const float*)d_in[2];
  const float* Wk      = (const float*)d_in[3];
  const float* Wv      = (const float*)d_in[4];
  const float* Wo      = (const float*)d_in[5];
  const float* bo      = (const float*)d_in[6];
  float* out = (float*)d_out;

  char* ws = (char*)d_ws;
  unsigned short* xb   = (unsigned short*)(ws);                 // 8 MB  x bf16 [4096][1024]
  unsigned short* wqkv = (unsigned short*)(ws + (8u  << 20));   // 6 MB  [Wq;Wk;Wv] bf16
  unsigned short* wob  = (unsigned short*)(ws + (14u << 20));   // 2 MB  Wo bf16
  unsigned short* qb   = (unsigned short*)(ws + (16u << 20));   // 8 MB  q [bh][t][d] (pre-scaled)
  unsigned short* kb   = (unsigned short*)(ws + (24u << 20));   // 8 MB  k [bh][t][d]
  unsigned short* vtb  = (unsigned short*)(ws + (32u << 20));   // 8 MB  v^T [bh][d][t]
  unsigned short* ab   = (unsigned short*)(ws + (40u << 20));   // 8 MB  attn-out [b*t][1024]

  convert_kernel<<<8192, 256, 0, stream>>>(x, Wq, Wk, Wv, Wo, xb, wqkv, wob);

  // fused Q,K,V projections: C[3072 chans][4096 tokens] = [Wq;Wk;Wv] @ x^T
  gemm_bt<1, 192, 128><<<dim3(16, 32), 256, 0, stream>>>(wqkv, xb, qb, kb, vtb, nullptr, nullptr);

  // attention
  attn_kernel<<<dim3(32, 16), 256, 0, stream>>>(qb, kb, vtb, padding, ab);

  // output projection: C[1024 chans][4096 tokens] = Wo @ attn^T -> out[t][chan]+bo
  gemm_bt<2, 64, 128><<<dim3(16, 32), 256, 0, stream>>>(wob, ab, nullptr, nullptr, nullptr, out, bo);
}